// Round 12
// baseline (34.762 us; speedup 1.0000x reference)
//
#include <hip/hip_runtime.h>
#include <hip/hip_bf16.h>

typedef __attribute__((ext_vector_type(8))) short bf16x8;
typedef __attribute__((ext_vector_type(4))) float f32x4;
typedef __attribute__((ext_vector_type(8))) _Float16 h8;
typedef __attribute__((ext_vector_type(2))) _Float16 h2;

#define N_PTS  500000
#define DIM    64
#define NCLUST 128
#define TILES  (N_PTS / 16)   // 31250, exact
#define NBLK   768            // 3 blocks/CU at <=170 VGPR, 48.5KB LDS
#define LOG2E  1.44269504088896f
#define LN2    0.69314718055994f

typedef const __attribute__((address_space(1))) char gchar;
typedef __attribute__((address_space(3))) char schar;
// async DMA global->LDS, 16B/lane, linear LDS dest (wave base + lane*16).
// offset arg always 0: displacements are folded into the pointers to avoid
// any ambiguity about which address the immediate offset applies to.
#define GLL16(gp, lp) \
    __builtin_amdgcn_global_load_lds((gchar*)(gp), (schar*)(lp), 16, 0, 0)
#define WAIT_VM(n)  asm volatile("s_waitcnt vmcnt(" #n ")" ::: "memory")
#define WAIT_LGKM() asm volatile("s_waitcnt lgkmcnt(0)" ::: "memory")

static __device__ __forceinline__ unsigned f2bf(float x) {
    union { float f; unsigned u; } un; un.f = x;
    unsigned u = un.u;
    u += 0x7fffu + ((u >> 16) & 1u);   // RNE
    return u >> 16;
}

static __device__ __forceinline__ float sq4(f32x4 v) {
    return v[0]*v[0] + v[1]*v[1] + v[2]*v[2] + v[3]*v[3];
}

static __device__ __forceinline__ bf16x8 pack8(f32x4 a, f32x4 b) {
    union { bf16x8 v; __hip_bfloat162 h[4]; } u;
    u.h[0] = __float22bfloat162_rn(make_float2(a[0], a[1]));
    u.h[1] = __float22bfloat162_rn(make_float2(a[2], a[3]));
    u.h[2] = __float22bfloat162_rn(make_float2(b[0], b[1]));
    u.h[3] = __float22bfloat162_rn(make_float2(b[2], b[3]));
    return u.v;
}

__global__ __launch_bounds__(256, 3) void kmeans_lse_kernel(
    const float* __restrict__ X, const float* __restrict__ centers,
    const float* __restrict__ vars_, const float* __restrict__ prs,
    const float* __restrict__ threshold, float* __restrict__ out)
{
    // Scaled centers c'_j = c_j/var_j*log2e as bf16, XOR-slot-swizzled (prologue only)
    __shared__ unsigned short sC[NCLUST * DIM];          // 16 KB
    // Per-cluster LSE constants as f16: block (j>>2): halfs [a-quad | b-quad]
    __shared__ __align__(16) _Float16 sABh[NCLUST * 2];  // 512 B
    // Per-wave double staging buffer: LDS[e] = tile[sigma(e)], sigma = XOR point-low3 into bits 4-6
    __shared__ __align__(16) char sStage[4][2][4096];    // 32 KB

    const int tid = threadIdx.x;
    {   // prologue: 2 threads per cluster row (halves)
        const int j = tid >> 1, h = tid & 1;
        const float inv = 1.0f / vars_[j];
        const float cscale = inv * LOG2E;
        float c2p = 0.0f;
        #pragma unroll
        for (int k = 32*h; k < 32*h + 32; k += 4) {
            float4 c = *(const float4*)(centers + j*DIM + k);
            c2p = fmaf(c.x, c.x, fmaf(c.y, c.y, fmaf(c.z, c.z, fmaf(c.w, c.w, c2p))));
            const int base = j*64 + (((k >> 3) ^ (j & 7)) << 3) + (k & 7);
            sC[base+0] = (unsigned short)f2bf(c.x * cscale);
            sC[base+1] = (unsigned short)f2bf(c.y * cscale);
            sC[base+2] = (unsigned short)f2bf(c.z * cscale);
            sC[base+3] = (unsigned short)f2bf(c.w * cscale);
        }
        c2p += __shfl_xor(c2p, 1);
        if (h == 0) {
            const float a = -0.5f * inv * LOG2E;
            const float b = fmaf(a, c2p, __log2f(prs[j]));
            sABh[(j>>2)*8 + (j&3)]     = (_Float16)a;
            sABh[(j>>2)*8 + 4 + (j&3)] = (_Float16)b;
        }
    }
    __syncthreads();

    const int lane = tid & 63;
    const int wid  = tid >> 6;
    const int g    = lane >> 4;   // k-chunk group (0..3)
    const int r    = lane & 15;   // point-in-tile (B col) / cluster-row (A row)

    // Center fragments -> registers for the whole loop (64 VGPRs).
    const unsigned co1 = (unsigned)r*64 + ((unsigned)(g ^ (r & 7)) << 3);
    const unsigned co2 = co1 ^ 32;
    bf16x8 Cf0[8], Cf1[8];
    #pragma unroll
    for (int t8 = 0; t8 < 8; ++t8) {
        Cf0[t8] = *(const bf16x8*)&sC[t8*1024 + co1];
        Cf1[t8] = *(const bf16x8*)&sC[t8*1024 + co2];
    }

    // swizzled read base (identical to R10): sigma(256r + 32g)
    const unsigned rb0 = (256u*(unsigned)r + 32u*(unsigned)g) ^ (((unsigned)(r & 7)) << 4);
    // per-lane inverse-swizzled GLOBAL source offsets (bytes within tile):
    //   KB0: 16*lane ^ (g<<4);  KB1: 1024 + (^64);  KB2/KB3: +2048 of those
    const unsigned gso0 = (16u*(unsigned)lane) ^ ((unsigned)g << 4);
    const unsigned gso1 = 1024u + (gso0 ^ 64u);

    char* bufA = &sStage[wid][0][0];
    char* bufB = &sStage[wid][1][0];
    const char* Xb = (const char*)X;

    const float thr = threshold[0];
    const int S = NBLK * 4;        // 3072 tile streams
    int t = blockIdx.x*4 + wid;

    // stage tile t -> bufA, t+S -> bufB (8 gll outstanding)
    {
        const char* p0 = Xb + (size_t)t*4096 + gso0;
        const char* p1 = Xb + (size_t)t*4096 + gso1;
        GLL16(p0,        bufA);        GLL16(p1,        bufA + 1024);
        GLL16(p0 + 2048, bufA + 2048); GLL16(p1 + 2048, bufA + 3072);
    }
    {
        const char* p0 = Xb + (size_t)(t + S)*4096 + gso0;
        const char* p1 = Xb + (size_t)(t + S)*4096 + gso1;
        GLL16(p0,        bufB);        GLL16(p1,        bufB + 1024);
        GLL16(p0 + 2048, bufB + 2048); GLL16(p1 + 2048, bufB + 3072);
    }

    // BODY: wait this buf's DMA, read frags, refill buf for tcur+2S, compute.
    // Steady queue between this buf's 4 glls and the wait: [store, 4 gll, store]
    // = 6 newer events, so vmcnt(6) guarantees this buf is complete.
#define BODY(buf, tcur, WN, MAYDRAIN) do {                                       \
        const int tp_ = (tcur) + 2*S;                                            \
        if (!(MAYDRAIN) || tp_ < TILES) { WAIT_VM(WN); } else { WAIT_VM(0); }    \
        __builtin_amdgcn_sched_barrier(0);                                       \
        f32x4 f1a = *(const f32x4*)((buf) + rb0);                                \
        f32x4 f1b = *(const f32x4*)((buf) + (rb0 ^ 16u));                        \
        f32x4 f2a = *(const f32x4*)((buf) + (rb0 ^ 128u));                       \
        f32x4 f2b = *(const f32x4*)((buf) + (rb0 ^ 144u));                       \
        WAIT_LGKM();                                                             \
        __builtin_amdgcn_sched_barrier(0);                                       \
        if (tp_ < TILES) {                                                       \
            const char* p0 = Xb + (size_t)tp_*4096 + gso0;                       \
            const char* p1 = Xb + (size_t)tp_*4096 + gso1;                       \
            GLL16(p0,        (buf));        GLL16(p1,        (buf) + 1024);      \
            GLL16(p0 + 2048, (buf) + 2048); GLL16(p1 + 2048, (buf) + 3072);      \
        }                                                                        \
        __builtin_amdgcn_sched_barrier(0);                                       \
        float ss = sq4(f1a) + sq4(f1b) + sq4(f2a) + sq4(f2b);                    \
        ss += __shfl_xor(ss, 16);                                                \
        ss += __shfl_xor(ss, 32);                                                \
        bf16x8 B0 = pack8(f1a, f1b);                                             \
        bf16x8 B1 = pack8(f2a, f2b);                                             \
        const h2 ss2 = {(_Float16)ss, (_Float16)ss};                             \
        f32x4 acc[8];                                                            \
        _Pragma("unroll")                                                        \
        for (int tt = 0; tt < 8; ++tt) {                                         \
            h8 ab = *(const volatile h8*)&sABh[tt*32 + g*8];                     \
            h2 i01 = __builtin_shufflevector(ab, ab, 0, 1) * ss2                 \
                   + __builtin_shufflevector(ab, ab, 4, 5);                      \
            h2 i23 = __builtin_shufflevector(ab, ab, 2, 3) * ss2                 \
                   + __builtin_shufflevector(ab, ab, 6, 7);                      \
            acc[tt][0] = (float)i01[0]; acc[tt][1] = (float)i01[1];              \
            acc[tt][2] = (float)i23[0]; acc[tt][3] = (float)i23[1];              \
            acc[tt] = __builtin_amdgcn_mfma_f32_16x16x32_bf16(Cf0[tt], B0, acc[tt], 0, 0, 0); \
            acc[tt] = __builtin_amdgcn_mfma_f32_16x16x32_bf16(Cf1[tt], B1, acc[tt], 0, 0, 0); \
        }                                                                        \
        float mx = acc[0][0];                                                    \
        _Pragma("unroll")                                                        \
        for (int tt = 0; tt < 8; ++tt)                                           \
            _Pragma("unroll")                                                    \
            for (int q = 0; q < 4; ++q) mx = fmaxf(mx, acc[tt][q]);              \
        mx = fmaxf(mx, __shfl_xor(mx, 16));                                      \
        mx = fmaxf(mx, __shfl_xor(mx, 32));                                      \
        float s0 = 0.f, s1 = 0.f, s2 = 0.f, s3 = 0.f;                            \
        _Pragma("unroll")                                                        \
        for (int tt = 0; tt < 8; ++tt) {                                         \
            s0 += __builtin_amdgcn_exp2f(acc[tt][0] - mx);                       \
            s1 += __builtin_amdgcn_exp2f(acc[tt][1] - mx);                       \
            s2 += __builtin_amdgcn_exp2f(acc[tt][2] - mx);                       \
            s3 += __builtin_amdgcn_exp2f(acc[tt][3] - mx);                       \
        }                                                                        \
        float sm = (s0 + s1) + (s2 + s3);                                        \
        sm += __shfl_xor(sm, 16);                                                \
        sm += __shfl_xor(sm, 32);                                                \
        if (lane < 16) {                                                         \
            out[(tcur)*16 + lane] =                                              \
                fmaf(mx + __builtin_amdgcn_logf(sm), LN2, -thr);                 \
        }                                                                        \
    } while (0)

    // peeled: conservative waits (over-waiting is safe; no drain possible:
    // t+3S <= 3071+9216 < 31250)
    BODY(bufA, t, 4, false);
    BODY(bufB, t + S, 4, false);
    t += 2*S;

    for (;;) {
        BODY(bufA, t, 6, true);
        if (t + S >= TILES) break;
        BODY(bufB, t + S, 6, true);
        t += 2*S;
        if (t >= TILES) break;
    }
#undef BODY
}

extern "C" void kernel_launch(void* const* d_in, const int* in_sizes, int n_in,
                              void* d_out, int out_size, void* d_ws, size_t ws_size,
                              hipStream_t stream) {
    const float* X         = (const float*)d_in[0];
    const float* centers   = (const float*)d_in[1];
    const float* vars_     = (const float*)d_in[2];
    const float* prs       = (const float*)d_in[3];
    const float* threshold = (const float*)d_in[4];
    float* out = (float*)d_out;
    (void)in_sizes; (void)n_in; (void)out_size; (void)d_ws; (void)ws_size;

    kmeans_lse_kernel<<<NBLK, 256, 0, stream>>>(X, centers, vars_, prs, threshold, out);
}